// Round 11
// baseline (449.698 us; speedup 1.0000x reference)
//
#include <hip/hip_runtime.h>
#include <hip/hip_cooperative_groups.h>

namespace cg = cooperative_groups;

#define NN 50000
#define NE 800000
#define CC 128
#define NL 3

typedef short bf16x8 __attribute__((ext_vector_type(8)));
typedef float f32x4 __attribute__((ext_vector_type(4)));
typedef unsigned int u32x4 __attribute__((ext_vector_type(4)));
union U16 { uint4 u; bf16x8 v; };

__device__ __forceinline__ float b2f(unsigned short u) {
  return __uint_as_float(((unsigned int)u) << 16);
}
__device__ __forceinline__ unsigned short f2b(float f) {
  unsigned int x = __float_as_uint(f);
  x += 0x7fffu + ((x >> 16) & 1u);   // round-to-nearest-even
  return (unsigned short)(x >> 16);
}

// nontemporal helpers: 'nt' = no L2 allocate, for read-once/write-once streams
__device__ __forceinline__ uint2 nt_load_u2(const uint2* p) {
  unsigned long long t = __builtin_nontemporal_load((const unsigned long long*)p);
  return make_uint2((unsigned)t, (unsigned)(t >> 32));
}
__device__ __forceinline__ void nt_store_u2(uint2* p, uint2 v) {
  unsigned long long t = (unsigned long long)v.x | ((unsigned long long)v.y << 32);
  __builtin_nontemporal_store(t, (unsigned long long*)p);
}
__device__ __forceinline__ void nt_store_u4(void* p, uint4 v) {
  u32x4 t = {v.x, v.y, v.z, v.w};
  __builtin_nontemporal_store(t, (u32x4*)p);
}
__device__ __forceinline__ void nt_store_f4(void* p, float a, float b, float c, float d) {
  f32x4 t = {a, b, c, d};
  __builtin_nontemporal_store(t, (f32x4*)p);
}

__device__ __forceinline__ int eidx(const int* ei, int row, int e, int f64) {
  return f64 ? ei[2 * ((size_t)row * NE + e)] : ei[(size_t)row * NE + e];
}

// ---- fused prep: per-block inline dtype flags + x->bf16 cvt + param cvt +
//      deg zero (1 dispatch).
// flags[0] = 1 if float tensors are bf16; flags[1] = 1 if edge_index int64.
#define NI4 (NN / 4)
__global__ __launch_bounds__(256) void k_prep(const void* __restrict__ xin,
                                              const int* __restrict__ ei,
                                              const void* lw, const void* lb,
                                              const void* emw, const void* emb,
                                              unsigned short* __restrict__ xb,
                                              unsigned short* __restrict__ wt,
                                              float* lbf, float* emwf, float* embf,
                                              int* __restrict__ deg,
                                              int* __restrict__ flags) {
  __shared__ int scnt, sany;
  const int tid = threadIdx.x;
  if (tid == 0) { scnt = 0; sany = 0; }
  __syncthreads();
  if (tid < 128) {
    unsigned short u = ((const unsigned short*)xin)[2 * tid];
    int ex = (u >> 7) & 0xFF;
    if (ex >= 0x70 && ex <= 0x8F) atomicAdd(&scnt, 1);
  }
  if (ei[2 * tid + 1] != 0) atomicOr(&sany, 1);
  __syncthreads();
  const int isbf = (scnt >= 64) ? 1 : 0;
  const int i = blockIdx.x * 256 + tid;
  if (i == 0) { flags[0] = isbf; flags[1] = (sany == 0) ? 1 : 0; }

  if (i < NI4) ((int4*)deg)[i] = make_int4(0, 0, 0, 0);

  if (i < NL * CC * CC) {
    unsigned short v = isbf ? ((const unsigned short*)lw)[i]
                            : f2b(((const float*)lw)[i]);
    const int l = i >> 14, r = i & 16383, k = r >> 7, n = r & 127;
    wt[l * 16384 + n * 128 + k] = v;
  }
  if (i < NL * CC)
    lbf[i] = isbf ? b2f(((const unsigned short*)lb)[i]) : ((const float*)lb)[i];
  if (i < NL * 8)
    emwf[i] = isbf ? b2f(((const unsigned short*)emw)[i]) : ((const float*)emw)[i];
  if (i < NL)
    embf[i] = isbf ? b2f(((const unsigned short*)emb)[i]) : ((const float*)emb)[i];

  if (!isbf && i < NN * CC / 8) {
    const float4 a = ((const float4*)xin)[2 * i];
    const float4 b = ((const float4*)xin)[2 * i + 1];
    uint4 o;
    o.x = (unsigned)f2b(a.x) | ((unsigned)f2b(a.y) << 16);
    o.y = (unsigned)f2b(a.z) | ((unsigned)f2b(a.w) << 16);
    o.z = (unsigned)f2b(b.x) | ((unsigned)f2b(b.y) << 16);
    o.w = (unsigned)f2b(b.z) | ((unsigned)f2b(b.w) << 16);
    ((uint4*)xb)[i] = o;
  }
}

// ---- cooperative CSR build: hist -> scan1 -> scan3 -> fill, one dispatch
//      (grid.sync between phases deletes 3 inter-dispatch gaps).
#define HT 8
#define BUILD_BLKS ((NE + HT * 256 - 1) / (HT * 256))   // 391
#define SCAN_BLKS ((NI4 + 255) / 256)                   // 49
__global__ __launch_bounds__(256) void k_build(const int* __restrict__ ei,
                                               const void* __restrict__ ea,
                                               const float* __restrict__ emwf,
                                               const float* __restrict__ embf,
                                               int* __restrict__ deg,
                                               int* __restrict__ offs,
                                               unsigned short* __restrict__ rank,
                                               int* __restrict__ bsum,
                                               uint2* __restrict__ esrt,
                                               const int* __restrict__ flags) {
  cg::grid_group grid = cg::this_grid();
  __shared__ int ls[256];
  __shared__ int sbase;
  const int tid = threadIdx.x;
  const int f64 = flags[1];
  const int tcount = gridDim.x * 256;

  // ---- phase 1: histogram + per-edge rank (8 edges/thread, grid-strided) ----
  {
    const int t = blockIdx.x * 256 + tid;
    int d[HT], r[HT];
#pragma unroll
    for (int k = 0; k < HT; ++k) {
      const int e = t + k * tcount;
      d[k] = (e < NE) ? eidx(ei, 1, e, f64) : -1;
    }
#pragma unroll
    for (int k = 0; k < HT; ++k)
      if (d[k] >= 0) r[k] = atomicAdd(&deg[d[k]], 1);
#pragma unroll
    for (int k = 0; k < HT; ++k) {
      const int e = t + k * tcount;
      if (e < NE) rank[e] = (unsigned short)r[k];
    }
  }
  grid.sync();

  // ---- phase 2: per-block inclusive scan (blocks 0..48) ----
  if (blockIdx.x < SCAN_BLKS) {
    const int g = blockIdx.x * 256 + tid;
    int4 d = make_int4(0, 0, 0, 0);
    if (g < NI4) d = ((const int4*)deg)[g];
    const int s = d.x + d.y + d.z + d.w;
    ls[tid] = s;
    __syncthreads();
#pragma unroll
    for (int off = 1; off < 256; off <<= 1) {
      int tmp = (tid >= off) ? ls[tid - off] : 0;
      __syncthreads();
      ls[tid] += tmp;
      __syncthreads();
    }
    const int excl = ls[tid] - s;
    if (g < NI4) {
      int4 o;
      o.x = excl; o.y = o.x + d.x; o.z = o.y + d.y; o.w = o.z + d.z;
      ((int4*)offs)[g] = o;
    }
    if (tid == 255) bsum[blockIdx.x] = ls[255];
  }
  grid.sync();

  // ---- phase 3: add cross-block bases (blocks 0..48) ----
  if (blockIdx.x < SCAN_BLKS) {
    if (tid == 0) {
      int run = 0;
      for (int b = 0; b < (int)blockIdx.x; ++b) run += bsum[b];
      sbase = run;
      if (blockIdx.x == 0) {
        int tot = 0;
        for (int b = 0; b < SCAN_BLKS; ++b) tot += bsum[b];
        offs[NN] = tot;
      }
    }
    __syncthreads();
    const int g = blockIdx.x * 256 + tid;
    if (g < NI4) {
      const int base = sbase;
      int4 o = ((int4*)offs)[g];
      o.x += base; o.y += base; o.z += base; o.w += base;
      ((int4*)offs)[g] = o;
    }
  }
  grid.sync();

  // ---- phase 4: fill (grid-strided), NT scatter-store of 8-B records ----
  const int isbf = flags[0];
  for (int e = blockIdx.x * 256 + tid; e < NE; e += tcount) {
    float a[8];
    if (isbf) {
      const uint4 v = ((const uint4*)ea)[e];
      unsigned int p[4] = {v.x, v.y, v.z, v.w};
#pragma unroll
      for (int q = 0; q < 4; ++q) {
        a[2 * q]     = __uint_as_float(p[q] << 16);
        a[2 * q + 1] = __uint_as_float(p[q] & 0xffff0000u);
      }
    } else {
      const float4 v0 = ((const float4*)ea)[2 * e];
      const float4 v1 = ((const float4*)ea)[2 * e + 1];
      a[0] = v0.x; a[1] = v0.y; a[2] = v0.z; a[3] = v0.w;
      a[4] = v1.x; a[5] = v1.y; a[6] = v1.z; a[7] = v1.w;
    }
    unsigned wb[NL];
#pragma unroll
    for (int l = 0; l < NL; ++l) {
      float z = embf[l];
#pragma unroll
      for (int k = 0; k < 8; ++k) z += a[k] * emwf[l * 8 + k];
      const float w = (z > 20.f) ? z : log1pf(expf(z));
      wb[l] = (unsigned)f2b(w);
    }
    const int d = eidx(ei, 1, e, f64);
    const int s = eidx(ei, 0, e, f64);
    const int pos = offs[d] + (int)rank[e];
    nt_store_u2(&esrt[pos],
                make_uint2((unsigned)s | (wb[0] << 16), wb[1] | (wb[2] << 16)));
  }
}

// ---- fused layer (round-8 proven structure): gather -> LDS A-tile ->
//      MFMA with LDS-staged B -> epilogue. 512 threads = 8 waves, 64 nodes.
//      Record loads are NT (read-once stream; don't evict x rows from L2).
#define LPAD 136
template<int LAYER>
__device__ __forceinline__ unsigned wbits(const uint2& p) {
  return LAYER == 0 ? (p.x & 0xffff0000u)
       : (LAYER == 1 ? (p.y << 16) : (p.y & 0xffff0000u));
}

template<int LAYER>
__global__ __launch_bounds__(512) void k_layer(const int* __restrict__ offs,
                                               const uint2* __restrict__ esrt,
                                               const unsigned short* xc_,
                                               const unsigned short* alt, int sel,
                                               const unsigned short* __restrict__ wt,
                                               const float* __restrict__ lbf,
                                               void* outp, int last,
                                               const int* __restrict__ flags,
                                               unsigned short* __restrict__ xout) {
  const unsigned short* xb = (sel && flags[0]) ? alt : xc_;
  __shared__ unsigned short shA[64 * LPAD];    // 17408 B (A tile / C tile)
  __shared__ unsigned short shB[128 * LPAD];   // 34816 B (W tile)
  const int tid = threadIdx.x;
  const int rb = blockIdx.x * 64;
  const unsigned short* wtl = wt + (size_t)LAYER * CC * CC;

  // stage B first: global loads issue before the gather phase, latency hides
  for (int u = tid; u < 2048; u += 512) {
    const int row = u >> 4, q = u & 15;
    *(uint4*)&shB[row * LPAD + q * 8] = *(const uint4*)&wtl[row * 128 + q * 8];
  }

  const int wid = tid >> 6;
  const int l = tid & 63;
  const int g = l >> 4;            // edge slot within 4-edge batch
  const int ch = (l & 15) * 8;     // 8 bf16 channels per lane

  // ---- gather phase: wave wid handles nodes rb + wid*8 .. +7 ----
  for (int i = 0; i < 8; ++i) {
    const int nl = wid * 8 + i;
    const int node = __builtin_amdgcn_readfirstlane(rb + nl);
    if (node >= NN) {
      if (l < 16) *(uint4*)&shA[nl * LPAD + ch] = make_uint4(0, 0, 0, 0);
      continue;
    }
    const int j0 = offs[node];
    const int j1 = offs[node + 1];
    const uint4 xi = *(const uint4*)&xb[(size_t)node * CC + ch];
    float ax[8];
#pragma unroll
    for (int q = 0; q < 8; ++q) ax[q] = 0.f;
    float sw = 0.f;

    for (int jc = j0; jc < j1; jc += 64) {
      const int cnt = j1 - jc;                 // uniform
      const int kk = (l < cnt) ? l : (cnt - 1);
      const uint2 rec = nt_load_u2(&esrt[jc + kk]);  // 64 records, NT
      const int srcl = (int)(rec.x & 0xffffu);
      const int wl = (int)wbits<LAYER>(rec);   // f32 bits (bf16 in high half)
      const int cc2 = (cnt > 64) ? 64 : cnt;
      const int nsb = (cc2 + 15) >> 4;         // uniform sub-batch count
      for (int b2 = 0; b2 < nsb; ++b2) {
        int srcw[4]; float wv[4];
#pragma unroll
        for (int b = 0; b < 4; ++b) {
          const int k = b2 * 16 + b * 4 + g;
          srcw[b] = __shfl(srcl, k);
          const float w = __uint_as_float((unsigned)__shfl(wl, k));
          wv[b] = (k < cnt) ? w : 0.f;
        }
        uint4 v[4];
#pragma unroll
        for (int b = 0; b < 4; ++b)
          v[b] = *(const uint4*)&xb[(size_t)(unsigned)srcw[b] * CC + ch];
#pragma unroll
        for (int b = 0; b < 4; ++b) {
          const float w = wv[b];
          const unsigned pv0 = v[b].x, pv1 = v[b].y, pv2 = v[b].z, pv3 = v[b].w;
          ax[0] += w * __uint_as_float(pv0 << 16);
          ax[1] += w * __uint_as_float(pv0 & 0xffff0000u);
          ax[2] += w * __uint_as_float(pv1 << 16);
          ax[3] += w * __uint_as_float(pv1 & 0xffff0000u);
          ax[4] += w * __uint_as_float(pv2 << 16);
          ax[5] += w * __uint_as_float(pv2 & 0xffff0000u);
          ax[6] += w * __uint_as_float(pv3 << 16);
          ax[7] += w * __uint_as_float(pv3 & 0xffff0000u);
          sw += w;
        }
      }
    }

    // combine the 4 edge-slot groups
#pragma unroll
    for (int q = 0; q < 8; ++q) {
      ax[q] += __shfl_xor(ax[q], 16);
      ax[q] += __shfl_xor(ax[q], 32);
    }
    sw += __shfl_xor(sw, 16);
    sw += __shfl_xor(sw, 32);

    if (l < 16) {
      float r[8];
      r[0] = ax[0] - sw * __uint_as_float(xi.x << 16);
      r[1] = ax[1] - sw * __uint_as_float(xi.x & 0xffff0000u);
      r[2] = ax[2] - sw * __uint_as_float(xi.y << 16);
      r[3] = ax[3] - sw * __uint_as_float(xi.y & 0xffff0000u);
      r[4] = ax[4] - sw * __uint_as_float(xi.z << 16);
      r[5] = ax[5] - sw * __uint_as_float(xi.z & 0xffff0000u);
      r[6] = ax[6] - sw * __uint_as_float(xi.w << 16);
      r[7] = ax[7] - sw * __uint_as_float(xi.w & 0xffff0000u);
      uint4 o;
      o.x = (unsigned)f2b(r[0]) | ((unsigned)f2b(r[1]) << 16);
      o.y = (unsigned)f2b(r[2]) | ((unsigned)f2b(r[3]) << 16);
      o.z = (unsigned)f2b(r[4]) | ((unsigned)f2b(r[5]) << 16);
      o.w = (unsigned)f2b(r[6]) | ((unsigned)f2b(r[7]) << 16);
      *(uint4*)&shA[nl * LPAD + ch] = o;
    }
  }
  __syncthreads();   // shA (A tile) + shB (W tile) ready

  // ---- MFMA phase: 64x128 C = 4x8 tiles of 16x16; wave wid owns
  //      row-tile rw = wid>>1, col-tiles cb..cb+3 with cb = (wid&1)*4.
  const int rw = wid >> 1;
  const int cb = (wid & 1) * 4;
  const int lr = l & 15;
  const int lk = (l >> 4) * 8;

  U16 afr[4];
#pragma unroll
  for (int kk = 0; kk < 4; ++kk)
    afr[kk].u = *(const uint4*)&shA[(rw * 16 + lr) * LPAD + kk * 32 + lk];
  __syncthreads();   // all A-frags in regs before shA is overwritten with C

  const float* lbp = lbf + LAYER * CC;
  f32x4 acc[4];
#pragma unroll
  for (int t = 0; t < 4; ++t) {
    acc[t] = (f32x4){0.f, 0.f, 0.f, 0.f};
#pragma unroll
    for (int kk = 0; kk < 4; ++kk) {
      U16 bfr;
      bfr.u = *(const uint4*)&shB[((cb + t) * 16 + lr) * LPAD + kk * 32 + lk];
      acc[t] = __builtin_amdgcn_mfma_f32_16x16x32_bf16(afr[kk].v, bfr.v, acc[t], 0, 0, 0);
    }
  }

#pragma unroll
  for (int t = 0; t < 4; ++t) {
    const float bv = lbp[(cb + t) * 16 + lr];
#pragma unroll
    for (int r = 0; r < 4; ++r) {
      const int tr = (l >> 4) * 4 + r;   // C/D: row = quad*4 + reg
      shA[(rw * 16 + tr) * LPAD + (cb + t) * 16 + lr] = f2b(acc[t][r] + bv);
    }
  }
  __syncthreads();

  // ---- epilogue: 64 rows x 16 uint4, 512 threads x 2 ----
  const int isbf = flags[0];
  for (int u = tid; u < 1024; u += 512) {
    const int row = u >> 4, q = u & 15;
    const int gr = rb + row;
    if (gr >= NN) continue;
    const uint4 yv = *(const uint4*)&shA[row * LPAD + q * 8];
    float y0 = __uint_as_float(yv.x << 16), y1 = __uint_as_float(yv.x & 0xffff0000u);
    float y2 = __uint_as_float(yv.y << 16), y3 = __uint_as_float(yv.y & 0xffff0000u);
    float y4 = __uint_as_float(yv.z << 16), y5 = __uint_as_float(yv.z & 0xffff0000u);
    float y6 = __uint_as_float(yv.w << 16), y7 = __uint_as_float(yv.w & 0xffff0000u);
    const size_t off = (size_t)gr * CC + q * 8;
    if (!last) {
      const uint4 rv = *(const uint4*)&xb[off];
      y0 = fmaxf(y0, 0.f) + __uint_as_float(rv.x << 16);
      y1 = fmaxf(y1, 0.f) + __uint_as_float(rv.x & 0xffff0000u);
      y2 = fmaxf(y2, 0.f) + __uint_as_float(rv.y << 16);
      y3 = fmaxf(y3, 0.f) + __uint_as_float(rv.y & 0xffff0000u);
      y4 = fmaxf(y4, 0.f) + __uint_as_float(rv.z << 16);
      y5 = fmaxf(y5, 0.f) + __uint_as_float(rv.z & 0xffff0000u);
      y6 = fmaxf(y6, 0.f) + __uint_as_float(rv.w << 16);
      y7 = fmaxf(y7, 0.f) + __uint_as_float(rv.w & 0xffff0000u);
      uint4 o;
      o.x = (unsigned)f2b(y0) | ((unsigned)f2b(y1) << 16);
      o.y = (unsigned)f2b(y2) | ((unsigned)f2b(y3) << 16);
      o.z = (unsigned)f2b(y4) | ((unsigned)f2b(y5) << 16);
      o.w = (unsigned)f2b(y6) | ((unsigned)f2b(y7) << 16);
      *(uint4*)&xout[off] = o;   // next layer reads this: keep cached
    } else if (isbf) {
      nt_store_u4(&((unsigned short*)outp)[off], yv);
    } else {
      nt_store_f4(&((float*)outp)[off], y0, y1, y2, y3);
      nt_store_f4(&((float*)outp)[off + 4], y4, y5, y6, y7);
    }
  }
}

extern "C" void kernel_launch(void* const* d_in, const int* in_sizes, int n_in,
                              void* d_out, int out_size, void* d_ws, size_t ws_size,
                              hipStream_t stream) {
  const unsigned short* x0 = (const unsigned short*)d_in[0];
  const int* ei = (const int*)d_in[1];

  const size_t nbuf = (size_t)NN * CC;
  unsigned short* xb0 = (unsigned short*)d_ws;
  unsigned short* xb1 = xb0 + nbuf;
  unsigned short* wt = xb1 + nbuf;
  uint2* esrt = (uint2*)(wt + (size_t)NL * CC * CC);
  int* deg = (int*)(esrt + NE);
  int* offs = deg + NN;
  unsigned short* rank = (unsigned short*)(offs + NN + 4);
  int* bsum = (int*)(rank + NE);
  float* lbf = (float*)(bsum + 64);
  float* emwf = lbf + (size_t)NL * CC;
  float* embf = emwf + NL * 8;
  int* flags = (int*)(embf + NL);
  const size_t need = (size_t)((char*)(flags + 2) - (char*)d_ws);
  if (ws_size < need) {
    hipMemsetAsync(d_out, 0, (size_t)out_size * 2, stream);
    return;
  }

  k_prep<<<(NN * CC / 8) / 256, 256, 0, stream>>>(
      d_in[0], ei, d_in[3], d_in[4], d_in[5], d_in[6],
      xb0, wt, lbf, emwf, embf, deg, flags);

  {
    const int* ei_p = ei;
    const void* ea_p = d_in[2];
    const float* emwf_p = emwf;
    const float* embf_p = embf;
    int* deg_p = deg;
    int* offs_p = offs;
    unsigned short* rank_p = rank;
    int* bsum_p = bsum;
    uint2* esrt_p = esrt;
    const int* flags_p = flags;
    void* args[] = {(void*)&ei_p, (void*)&ea_p, (void*)&emwf_p, (void*)&embf_p,
                    (void*)&deg_p, (void*)&offs_p, (void*)&rank_p,
                    (void*)&bsum_p, (void*)&esrt_p, (void*)&flags_p};
    hipLaunchCooperativeKernel((void*)k_build, dim3(BUILD_BLKS), dim3(256),
                               args, 0, stream);
  }

  const int LBLKS = (NN + 63) / 64;   // 782
  unsigned short* xc = xb0;
  unsigned short* xo = xb1;
  for (int layer = 0; layer < NL; ++layer) {
    const int sel = (layer == 0) ? 1 : 0;
    const int last = (layer == NL - 1) ? 1 : 0;
    if (layer == 0)
      k_layer<0><<<LBLKS, 512, 0, stream>>>(offs, esrt, xc, x0, sel, wt, lbf,
                                            d_out, last, flags, xo);
    else if (layer == 1)
      k_layer<1><<<LBLKS, 512, 0, stream>>>(offs, esrt, xc, x0, sel, wt, lbf,
                                            d_out, last, flags, xo);
    else
      k_layer<2><<<LBLKS, 512, 0, stream>>>(offs, esrt, xc, x0, sel, wt, lbf,
                                            d_out, last, flags, xo);
    unsigned short* t = xc; xc = xo; xo = t;
  }
}

// Round 12
// 291.927 us; speedup vs baseline: 1.5404x; 1.5404x over previous
//
#include <hip/hip_runtime.h>

#define NN 50000
#define NE 800000
#define CC 128
#define NL 3

typedef short bf16x8 __attribute__((ext_vector_type(8)));
typedef float f32x4 __attribute__((ext_vector_type(4)));
union U16 { uint4 u; bf16x8 v; };

__device__ __forceinline__ float b2f(unsigned short u) {
  return __uint_as_float(((unsigned int)u) << 16);
}
__device__ __forceinline__ unsigned short f2b(float f) {
  unsigned int x = __float_as_uint(f);
  x += 0x7fffu + ((x >> 16) & 1u);   // round-to-nearest-even
  return (unsigned short)(x >> 16);
}

__device__ __forceinline__ int eidx(const int* ei, int row, int e, int f64) {
  return f64 ? ei[2 * ((size_t)row * NE + e)] : ei[(size_t)row * NE + e];
}

// ---- fused prep: per-block inline dtype flags + x->bf16 cvt + param cvt +
//      deg zero (1 dispatch instead of 4).
// flags[0] = 1 if float tensors are bf16; flags[1] = 1 if edge_index int64.
#define NI4 (NN / 4)
__global__ __launch_bounds__(256) void k_prep(const void* __restrict__ xin,
                                              const int* __restrict__ ei,
                                              const void* lw, const void* lb,
                                              const void* emw, const void* emb,
                                              unsigned short* __restrict__ xb,
                                              unsigned short* __restrict__ wt,
                                              float* lbf, float* emwf, float* embf,
                                              int* __restrict__ deg,
                                              int* __restrict__ flags) {
  __shared__ int scnt, sany;
  const int tid = threadIdx.x;
  if (tid == 0) { scnt = 0; sany = 0; }
  __syncthreads();
  if (tid < 128) {
    unsigned short u = ((const unsigned short*)xin)[2 * tid];
    int ex = (u >> 7) & 0xFF;
    if (ex >= 0x70 && ex <= 0x8F) atomicAdd(&scnt, 1);
  }
  if (ei[2 * tid + 1] != 0) atomicOr(&sany, 1);
  __syncthreads();
  const int isbf = (scnt >= 64) ? 1 : 0;
  const int i = blockIdx.x * 256 + tid;
  if (i == 0) { flags[0] = isbf; flags[1] = (sany == 0) ? 1 : 0; }

  if (i < NI4) ((int4*)deg)[i] = make_int4(0, 0, 0, 0);

  if (i < NL * CC * CC) {
    unsigned short v = isbf ? ((const unsigned short*)lw)[i]
                            : f2b(((const float*)lw)[i]);
    const int l = i >> 14, r = i & 16383, k = r >> 7, n = r & 127;
    wt[l * 16384 + n * 128 + k] = v;
  }
  if (i < NL * CC)
    lbf[i] = isbf ? b2f(((const unsigned short*)lb)[i]) : ((const float*)lb)[i];
  if (i < NL * 8)
    emwf[i] = isbf ? b2f(((const unsigned short*)emw)[i]) : ((const float*)emw)[i];
  if (i < NL)
    embf[i] = isbf ? b2f(((const unsigned short*)emb)[i]) : ((const float*)emb)[i];

  if (!isbf && i < NN * CC / 8) {
    const float4 a = ((const float4*)xin)[2 * i];
    const float4 b = ((const float4*)xin)[2 * i + 1];
    uint4 o;
    o.x = (unsigned)f2b(a.x) | ((unsigned)f2b(a.y) << 16);
    o.y = (unsigned)f2b(a.z) | ((unsigned)f2b(a.w) << 16);
    o.z = (unsigned)f2b(b.x) | ((unsigned)f2b(b.y) << 16);
    o.w = (unsigned)f2b(b.z) | ((unsigned)f2b(b.w) << 16);
    ((uint4*)xb)[i] = o;
  }
}

// ---- CSR build: histogram of dst + per-edge rank within bucket.
#define HT 8
#define HIST_BLKS ((NE + HT * 256 - 1) / (HT * 256))
__global__ __launch_bounds__(256) void k_hist(const int* __restrict__ ei,
                                              int* __restrict__ deg,
                                              unsigned short* __restrict__ rank,
                                              const int* __restrict__ flags) {
  const int f64 = flags[1];
  const int nt = gridDim.x * 256;
  const int t = blockIdx.x * 256 + threadIdx.x;
  int d[HT], r[HT];
#pragma unroll
  for (int k = 0; k < HT; ++k) {
    const int e = t + k * nt;
    d[k] = (e < NE) ? eidx(ei, 1, e, f64) : -1;
  }
#pragma unroll
  for (int k = 0; k < HT; ++k)
    if (d[k] >= 0) r[k] = atomicAdd(&deg[d[k]], 1);
#pragma unroll
  for (int k = 0; k < HT; ++k) {
    const int e = t + k * nt;
    if (e < NE) rank[e] = (unsigned short)r[k];
  }
}

// ---- 2-phase device-wide exclusive scan over deg[NN] ----
#define SCAN_BLKS ((NI4 + 255) / 256)   // 49
__global__ __launch_bounds__(256) void k_scan1(const int* __restrict__ deg,
                                               int* __restrict__ offs,
                                               int* __restrict__ bsum) {
  __shared__ int ls[256];
  const int t = threadIdx.x;
  const int g = blockIdx.x * 256 + t;
  int4 d = make_int4(0, 0, 0, 0);
  if (g < NI4) d = ((const int4*)deg)[g];
  const int s = d.x + d.y + d.z + d.w;
  ls[t] = s;
  __syncthreads();
#pragma unroll
  for (int off = 1; off < 256; off <<= 1) {
    int tmp = (t >= off) ? ls[t - off] : 0;
    __syncthreads();
    ls[t] += tmp;
    __syncthreads();
  }
  const int excl = ls[t] - s;
  if (g < NI4) {
    int4 o;
    o.x = excl; o.y = o.x + d.x; o.z = o.y + d.y; o.w = o.z + d.z;
    ((int4*)offs)[g] = o;
  }
  if (t == 255) bsum[blockIdx.x] = ls[255];
}

// scan2+scan3 merged: each block derives its own base from bsum (<=48 adds).
__global__ __launch_bounds__(256) void k_scan3(int* __restrict__ offs,
                                               const int* __restrict__ bsum) {
  __shared__ int sbase;
  const int g = blockIdx.x * 256 + threadIdx.x;
  if (threadIdx.x == 0) {
    int run = 0;
    for (int b = 0; b < (int)blockIdx.x; ++b) run += bsum[b];
    sbase = run;
    if (blockIdx.x == 0) {
      int tot = 0;
      for (int b = 0; b < SCAN_BLKS; ++b) tot += bsum[b];
      offs[NN] = tot;
    }
  }
  __syncthreads();
  if (g >= NI4) return;
  const int base = sbase;
  int4 o = ((int4*)offs)[g];
  o.x += base; o.y += base; o.z += base; o.w += base;
  ((int4*)offs)[g] = o;
}

// ---- CSR fill, ATOMIC-FREE: pos = offs[dst] + rank[e].
//      8-byte record: (src:16 | w0.bf16:16, w1.bf16:16 | w2.bf16:16).
__global__ __launch_bounds__(256) void k_fill(const int* __restrict__ ei,
                                              const void* __restrict__ ea,
                                              const float* __restrict__ emwf,
                                              const float* __restrict__ embf,
                                              const int* __restrict__ offs,
                                              const unsigned short* __restrict__ rank,
                                              uint2* __restrict__ esrt,
                                              const int* __restrict__ flags) {
  int e = blockIdx.x * 256 + threadIdx.x;
  if (e >= NE) return;
  float a[8];
  if (flags[0]) {
    const uint4 v = ((const uint4*)ea)[e];
    unsigned int p[4] = {v.x, v.y, v.z, v.w};
#pragma unroll
    for (int q = 0; q < 4; ++q) {
      a[2 * q]     = __uint_as_float(p[q] << 16);
      a[2 * q + 1] = __uint_as_float(p[q] & 0xffff0000u);
    }
  } else {
    const float4 v0 = ((const float4*)ea)[2 * e];
    const float4 v1 = ((const float4*)ea)[2 * e + 1];
    a[0] = v0.x; a[1] = v0.y; a[2] = v0.z; a[3] = v0.w;
    a[4] = v1.x; a[5] = v1.y; a[6] = v1.z; a[7] = v1.w;
  }
  unsigned wb[NL];
#pragma unroll
  for (int l = 0; l < NL; ++l) {
    float z = embf[l];
#pragma unroll
    for (int k = 0; k < 8; ++k) z += a[k] * emwf[l * 8 + k];
    const float w = (z > 20.f) ? z : log1pf(expf(z));
    wb[l] = (unsigned)f2b(w);
  }
  const int f64 = flags[1];
  const int d = eidx(ei, 1, e, f64);
  const int s = eidx(ei, 0, e, f64);
  const int pos = offs[d] + (int)rank[e];
  esrt[pos] = make_uint2((unsigned)s | (wb[0] << 16), wb[1] | (wb[2] << 16));
}

// ---- fused layer (round-8 proven structure): gather -> LDS A-tile ->
//      MFMA with LDS-staged B -> epilogue. 512 threads = 8 waves, 64 nodes.
#define LPAD 136
template<int LAYER>
__device__ __forceinline__ unsigned wbits(const uint2& p) {
  return LAYER == 0 ? (p.x & 0xffff0000u)
       : (LAYER == 1 ? (p.y << 16) : (p.y & 0xffff0000u));
}

template<int LAYER>
__global__ __launch_bounds__(512) void k_layer(const int* __restrict__ offs,
                                               const uint2* __restrict__ esrt,
                                               const unsigned short* xc_,
                                               const unsigned short* alt, int sel,
                                               const unsigned short* __restrict__ wt,
                                               const float* __restrict__ lbf,
                                               void* outp, int last,
                                               const int* __restrict__ flags,
                                               unsigned short* __restrict__ xout) {
  const unsigned short* xb = (sel && flags[0]) ? alt : xc_;
  __shared__ unsigned short shA[64 * LPAD];    // 17408 B (A tile / C tile)
  __shared__ unsigned short shB[128 * LPAD];   // 34816 B (W tile)
  const int tid = threadIdx.x;
  const int rb = blockIdx.x * 64;
  const unsigned short* wtl = wt + (size_t)LAYER * CC * CC;

  // stage B first: global loads issue before the gather phase, latency hides
  for (int u = tid; u < 2048; u += 512) {
    const int row = u >> 4, q = u & 15;
    *(uint4*)&shB[row * LPAD + q * 8] = *(const uint4*)&wtl[row * 128 + q * 8];
  }

  const int wid = tid >> 6;
  const int l = tid & 63;
  const int g = l >> 4;            // edge slot within 4-edge batch
  const int ch = (l & 15) * 8;     // 8 bf16 channels per lane

  // ---- gather phase: wave wid handles nodes rb + wid*8 .. +7 ----
  for (int i = 0; i < 8; ++i) {
    const int nl = wid * 8 + i;
    const int node = __builtin_amdgcn_readfirstlane(rb + nl);
    if (node >= NN) {
      if (l < 16) *(uint4*)&shA[nl * LPAD + ch] = make_uint4(0, 0, 0, 0);
      continue;
    }
    const int j0 = offs[node];
    const int j1 = offs[node + 1];
    const uint4 xi = *(const uint4*)&xb[(size_t)node * CC + ch];
    float ax[8];
#pragma unroll
    for (int q = 0; q < 8; ++q) ax[q] = 0.f;
    float sw = 0.f;

    for (int jc = j0; jc < j1; jc += 64) {
      const int cnt = j1 - jc;                 // uniform
      const int kk = (l < cnt) ? l : (cnt - 1);
      const uint2 rec = esrt[jc + kk];         // 64 records in one instr
      const int srcl = (int)(rec.x & 0xffffu);
      const int wl = (int)wbits<LAYER>(rec);   // f32 bits (bf16 in high half)
      const int cc2 = (cnt > 64) ? 64 : cnt;
      const int nsb = (cc2 + 15) >> 4;         // uniform sub-batch count
      for (int b2 = 0; b2 < nsb; ++b2) {
        int srcw[4]; float wv[4];
#pragma unroll
        for (int b = 0; b < 4; ++b) {
          const int k = b2 * 16 + b * 4 + g;
          srcw[b] = __shfl(srcl, k);
          const float w = __uint_as_float((unsigned)__shfl(wl, k));
          wv[b] = (k < cnt) ? w : 0.f;
        }
        uint4 v[4];
#pragma unroll
        for (int b = 0; b < 4; ++b)
          v[b] = *(const uint4*)&xb[(size_t)(unsigned)srcw[b] * CC + ch];
#pragma unroll
        for (int b = 0; b < 4; ++b) {
          const float w = wv[b];
          const unsigned pv0 = v[b].x, pv1 = v[b].y, pv2 = v[b].z, pv3 = v[b].w;
          ax[0] += w * __uint_as_float(pv0 << 16);
          ax[1] += w * __uint_as_float(pv0 & 0xffff0000u);
          ax[2] += w * __uint_as_float(pv1 << 16);
          ax[3] += w * __uint_as_float(pv1 & 0xffff0000u);
          ax[4] += w * __uint_as_float(pv2 << 16);
          ax[5] += w * __uint_as_float(pv2 & 0xffff0000u);
          ax[6] += w * __uint_as_float(pv3 << 16);
          ax[7] += w * __uint_as_float(pv3 & 0xffff0000u);
          sw += w;
        }
      }
    }

    // combine the 4 edge-slot groups
#pragma unroll
    for (int q = 0; q < 8; ++q) {
      ax[q] += __shfl_xor(ax[q], 16);
      ax[q] += __shfl_xor(ax[q], 32);
    }
    sw += __shfl_xor(sw, 16);
    sw += __shfl_xor(sw, 32);

    if (l < 16) {
      float r[8];
      r[0] = ax[0] - sw * __uint_as_float(xi.x << 16);
      r[1] = ax[1] - sw * __uint_as_float(xi.x & 0xffff0000u);
      r[2] = ax[2] - sw * __uint_as_float(xi.y << 16);
      r[3] = ax[3] - sw * __uint_as_float(xi.y & 0xffff0000u);
      r[4] = ax[4] - sw * __uint_as_float(xi.z << 16);
      r[5] = ax[5] - sw * __uint_as_float(xi.z & 0xffff0000u);
      r[6] = ax[6] - sw * __uint_as_float(xi.w << 16);
      r[7] = ax[7] - sw * __uint_as_float(xi.w & 0xffff0000u);
      uint4 o;
      o.x = (unsigned)f2b(r[0]) | ((unsigned)f2b(r[1]) << 16);
      o.y = (unsigned)f2b(r[2]) | ((unsigned)f2b(r[3]) << 16);
      o.z = (unsigned)f2b(r[4]) | ((unsigned)f2b(r[5]) << 16);
      o.w = (unsigned)f2b(r[6]) | ((unsigned)f2b(r[7]) << 16);
      *(uint4*)&shA[nl * LPAD + ch] = o;
    }
  }
  __syncthreads();   // shA (A tile) + shB (W tile) ready

  // ---- MFMA phase: 64x128 C = 4x8 tiles of 16x16; wave wid owns
  //      row-tile rw = wid>>1, col-tiles cb..cb+3 with cb = (wid&1)*4.
  const int rw = wid >> 1;
  const int cb = (wid & 1) * 4;
  const int lr = l & 15;
  const int lk = (l >> 4) * 8;

  U16 afr[4];
#pragma unroll
  for (int kk = 0; kk < 4; ++kk)
    afr[kk].u = *(const uint4*)&shA[(rw * 16 + lr) * LPAD + kk * 32 + lk];
  __syncthreads();   // all A-frags in regs before shA is overwritten with C

  const float* lbp = lbf + LAYER * CC;
  f32x4 acc[4];
#pragma unroll
  for (int t = 0; t < 4; ++t) {
    acc[t] = (f32x4){0.f, 0.f, 0.f, 0.f};
#pragma unroll
    for (int kk = 0; kk < 4; ++kk) {
      U16 bfr;
      bfr.u = *(const uint4*)&shB[((cb + t) * 16 + lr) * LPAD + kk * 32 + lk];
      acc[t] = __builtin_amdgcn_mfma_f32_16x16x32_bf16(afr[kk].v, bfr.v, acc[t], 0, 0, 0);
    }
  }

#pragma unroll
  for (int t = 0; t < 4; ++t) {
    const float bv = lbp[(cb + t) * 16 + lr];
#pragma unroll
    for (int r = 0; r < 4; ++r) {
      const int tr = (l >> 4) * 4 + r;   // C/D: row = quad*4 + reg
      shA[(rw * 16 + tr) * LPAD + (cb + t) * 16 + lr] = f2b(acc[t][r] + bv);
    }
  }
  __syncthreads();

  // ---- epilogue: 64 rows x 16 uint4, 512 threads x 2 ----
  const int isbf = flags[0];
  for (int u = tid; u < 1024; u += 512) {
    const int row = u >> 4, q = u & 15;
    const int gr = rb + row;
    if (gr >= NN) continue;
    const uint4 yv = *(const uint4*)&shA[row * LPAD + q * 8];
    float y0 = __uint_as_float(yv.x << 16), y1 = __uint_as_float(yv.x & 0xffff0000u);
    float y2 = __uint_as_float(yv.y << 16), y3 = __uint_as_float(yv.y & 0xffff0000u);
    float y4 = __uint_as_float(yv.z << 16), y5 = __uint_as_float(yv.z & 0xffff0000u);
    float y6 = __uint_as_float(yv.w << 16), y7 = __uint_as_float(yv.w & 0xffff0000u);
    const size_t off = (size_t)gr * CC + q * 8;
    if (!last) {
      const uint4 rv = *(const uint4*)&xb[off];
      y0 = fmaxf(y0, 0.f) + __uint_as_float(rv.x << 16);
      y1 = fmaxf(y1, 0.f) + __uint_as_float(rv.x & 0xffff0000u);
      y2 = fmaxf(y2, 0.f) + __uint_as_float(rv.y << 16);
      y3 = fmaxf(y3, 0.f) + __uint_as_float(rv.y & 0xffff0000u);
      y4 = fmaxf(y4, 0.f) + __uint_as_float(rv.z << 16);
      y5 = fmaxf(y5, 0.f) + __uint_as_float(rv.z & 0xffff0000u);
      y6 = fmaxf(y6, 0.f) + __uint_as_float(rv.w << 16);
      y7 = fmaxf(y7, 0.f) + __uint_as_float(rv.w & 0xffff0000u);
      uint4 o;
      o.x = (unsigned)f2b(y0) | ((unsigned)f2b(y1) << 16);
      o.y = (unsigned)f2b(y2) | ((unsigned)f2b(y3) << 16);
      o.z = (unsigned)f2b(y4) | ((unsigned)f2b(y5) << 16);
      o.w = (unsigned)f2b(y6) | ((unsigned)f2b(y7) << 16);
      *(uint4*)&xout[off] = o;
    } else if (isbf) {
      *(uint4*)&((unsigned short*)outp)[off] = yv;
    } else {
      *(float4*)&((float*)outp)[off] = make_float4(y0, y1, y2, y3);
      *(float4*)&((float*)outp)[off + 4] = make_float4(y4, y5, y6, y7);
    }
  }
}

extern "C" void kernel_launch(void* const* d_in, const int* in_sizes, int n_in,
                              void* d_out, int out_size, void* d_ws, size_t ws_size,
                              hipStream_t stream) {
  const unsigned short* x0 = (const unsigned short*)d_in[0];
  const int* ei = (const int*)d_in[1];

  const size_t nbuf = (size_t)NN * CC;
  unsigned short* xb0 = (unsigned short*)d_ws;
  unsigned short* xb1 = xb0 + nbuf;
  unsigned short* wt = xb1 + nbuf;
  uint2* esrt = (uint2*)(wt + (size_t)NL * CC * CC);
  int* deg = (int*)(esrt + NE);
  int* offs = deg + NN;
  unsigned short* rank = (unsigned short*)(offs + NN + 4);
  int* bsum = (int*)(rank + NE);
  float* lbf = (float*)(bsum + 64);
  float* emwf = lbf + (size_t)NL * CC;
  float* embf = emwf + NL * 8;
  int* flags = (int*)(embf + NL);
  const size_t need = (size_t)((char*)(flags + 2) - (char*)d_ws);
  if (ws_size < need) {
    hipMemsetAsync(d_out, 0, (size_t)out_size * 2, stream);
    return;
  }

  k_prep<<<(NN * CC / 8) / 256, 256, 0, stream>>>(
      d_in[0], ei, d_in[3], d_in[4], d_in[5], d_in[6],
      xb0, wt, lbf, emwf, embf, deg, flags);
  k_hist<<<HIST_BLKS, 256, 0, stream>>>(ei, deg, rank, flags);
  k_scan1<<<SCAN_BLKS, 256, 0, stream>>>(deg, offs, bsum);
  k_scan3<<<SCAN_BLKS, 256, 0, stream>>>(offs, bsum);
  k_fill<<<(NE + 255) / 256, 256, 0, stream>>>(ei, d_in[2], emwf, embf,
                                               offs, rank, esrt, flags);

  const int LBLKS = (NN + 63) / 64;   // 782
  unsigned short* xc = xb0;
  unsigned short* xo = xb1;
  for (int layer = 0; layer < NL; ++layer) {
    const int sel = (layer == 0) ? 1 : 0;
    const int last = (layer == NL - 1) ? 1 : 0;
    if (layer == 0)
      k_layer<0><<<LBLKS, 512, 0, stream>>>(offs, esrt, xc, x0, sel, wt, lbf,
                                            d_out, last, flags, xo);
    else if (layer == 1)
      k_layer<1><<<LBLKS, 512, 0, stream>>>(offs, esrt, xc, x0, sel, wt, lbf,
                                            d_out, last, flags, xo);
    else
      k_layer<2><<<LBLKS, 512, 0, stream>>>(offs, esrt, xc, x0, sel, wt, lbf,
                                            d_out, last, flags, xo);
    unsigned short* t = xc; xc = xo; xo = t;
  }
}